// Round 7
// baseline (157.348 us; speedup 1.0000x reference)
//
#include <hip/hip_runtime.h>

#define BATCH 16384
#define DIM   512
#define UNITS 1024
// GAMMA = 0.5 folded into epilogue: out = exp(cross - 0.5*xsq - 0.5*musq)

typedef float v16f __attribute__((ext_vector_type(16)));

#define MFMA_F8(a, b, c) __builtin_amdgcn_mfma_f32_32x32x16_fp8_fp8((a), (b), (c), 0, 0, 0)

static __device__ __forceinline__ int2 cvt8(const float4 f0, const float4 f1) {
    int lo = __builtin_amdgcn_cvt_pk_fp8_f32(f0.x, f0.y, 0, false);
    lo     = __builtin_amdgcn_cvt_pk_fp8_f32(f0.z, f0.w, lo, true);
    int hi = __builtin_amdgcn_cvt_pk_fp8_f32(f1.x, f1.y, 0, false);
    hi     = __builtin_amdgcn_cvt_pk_fp8_f32(f1.z, f1.w, hi, true);
    return make_int2(lo, hi);
}
static __device__ __forceinline__ float dot8(const float4 f0, const float4 f1) {
    return f0.x * f0.x + f0.y * f0.y + f0.z * f0.z + f0.w * f0.w
         + f1.x * f1.x + f1.y * f1.y + f1.z * f1.z + f1.w * f1.w;
}

// Fused producer-consumer RBF kernel. 1024 blocks x 256 threads (4 waves),
// 37.6 KB LDS + launch_bounds(256,4) -> 4 blocks/CU -> the ENTIRE grid is
// co-resident (1024 = 4*256): per-panel flag spin cannot deadlock.
// Grid: xcd=b&7, j=b>>3, mt=xcd*8+(j&7), nt=j>>3. Block tile 256M x 64N.
//
// Phases:
//  P0/P1: convert THIS block's 16 A-rows (r0 = mt*256+nt*16) to fragment-
//         order fp8 -> A8f global (+ xsq). All 1024 blocks together cover A
//         exactly once; the 16 blocks of panel mt (same XCD under round-robin)
//         produce the panel they later consume (L2-local).
//  P2:    t0 release-adds done[mt] (agent scope: cross-XCD safe, G16).
//  P3:    stage B-slice (mu cols [nt*64,+64), fp32->fp8 fragment order) into
//         32 KB LDS overlaying the dead A-stage buffer; musq partials in LDS.
//         This overlaps siblings' A-prep -> hides the old prep->gemm latency.
//  P4:    t0 spins (relaxed) until done[mt]==16, one acquire load to
//         invalidate stale caches (poisoned A8f lines), barrier.
//  P5:    R6 K-loop unchanged: 2 passes x (32 kw x {1 global A, 2 ds, 2 MFMA})
//         + immediate exp/store epilogue per pass.
// A8f/xsq layouts identical to R6; B fragment layout identical to B8f's.
__global__ __launch_bounds__(256, 4)
void rbf_fused_pc_kernel(const float* __restrict__ in, const float* __restrict__ mu,
                         unsigned char* __restrict__ A8f, float* __restrict__ xsq,
                         int* __restrict__ done, float* __restrict__ out) {
    __shared__ __attribute__((aligned(16))) unsigned char smem[37632];
    float* ldsA = (float*)smem;                  // [16][516] fp32 (P0-P1 only)
    unsigned char* Bs = smem;                    // 32 KB fp8 (P3+), overlays ldsA
    float* redX = (float*)(smem + 33024);        // [16][64] xsq partials
    float* mred = (float*)(smem + 37120);        // [64][2] musq partials

    const int t  = threadIdx.x;
    const int l  = t & 63;
    const int w  = t >> 6;          // wave 0..3
    const int ln = l & 31;
    const int h  = l >> 5;

    const int b   = blockIdx.x;     // 0..1023
    const int xcd = b & 7;
    const int j   = b >> 3;         // 0..127
    const int mt  = xcd * 8 + (j & 7);
    const int nt  = j >> 3;         // 0..15
    const int m0  = mt * 256;
    const int n0  = nt * 64;
    const int r0  = m0 + nt * 16;   // this block's 16 A-rows
    const int c   = r0 >> 5;        // A8f chunk
    const int ro  = (nt & 1) * 16;  // row offset within chunk

    // ---- P0: load 16 rows of A into LDS (coalesced float4) ----
    {
        const float4* src = (const float4*)(in + (size_t)r0 * DIM);
        float4* l4 = (float4*)ldsA;
#pragma unroll
        for (int i = 0; i < 8; i++) {
            const int f = i * 256 + t;                   // float4 id 0..2047
            l4[(f >> 7) * 129 + (f & 127)] = src[f];
        }
    }
    __syncthreads();

    // ---- P1: fragment-order fp8 convert + xsq partials ----
    {
        const int kw = t >> 3, sub = t & 7;
        const int hh = sub & 1, rq = sub >> 1;
#pragma unroll
        for (int i = 0; i < 4; i++) {
            const int rloc = rq * 4 + i;                 // row-in-block 0..15
            const float* p = ldsA + rloc * 516 + kw * 16 + hh * 8;
            float4 f0 = *(const float4*)p;
            float4 f1 = *(const float4*)(p + 4);
            redX[rloc * 64 + kw * 2 + hh] = dot8(f0, f1);
            *(int2*)(A8f + (((size_t)c * 32 + kw) * 64 + hh * 32 + ro + rloc) * 8)
                = cvt8(f0, f1);
        }
    }
    __syncthreads();

    // ---- P2: xsq for our 16 rows, then signal panel progress ----
    if (t < 16) {
        float a = 0.f;
#pragma unroll
        for (int i = 0; i < 64; i++) a += redX[t * 64 + i];
        xsq[r0 + t] = a;
    }
    __syncthreads();                                     // all A8f+xsq in L2
    if (t == 0)
        __hip_atomic_fetch_add(done + mt, 1, __ATOMIC_RELEASE,
                               __HIP_MEMORY_SCOPE_AGENT);

    // ---- P3: stage B-slice (64 cols) from mu into LDS fp8 fragments ----
    {
        const int ng = w >> 1;              // 0..1: 32-col group
        const int kq = w & 1;               // k-half (256 k)
        const float* msrc = mu + (size_t)(kq * 256 + h * 8) * UNITS + n0 + ng * 32 + ln;
        unsigned char* bdst = Bs + (((ng * 32 + kq * 16) * 64) + l) * 8;
        float s = 0.f;
#pragma unroll 4
        for (int kk = 0; kk < 16; kk++) {
            float v[8];
#pragma unroll
            for (int jj = 0; jj < 8; jj++) v[jj] = msrc[(size_t)(kk * 16 + jj) * UNITS];
#pragma unroll
            for (int jj = 0; jj < 8; jj++) s += v[jj] * v[jj];
            *(int2*)(bdst + kk * 512) =
                cvt8(make_float4(v[0], v[1], v[2], v[3]),
                     make_float4(v[4], v[5], v[6], v[7]));
        }
        s += __shfl_xor(s, 32, 64);         // combine h halves per column
        if (h == 0) mred[(ng * 32 + ln) * 2 + kq] = s;
    }
    __syncthreads();                                     // Bs + mred ready

    // ---- P4: wait for the whole m-panel (16 producer blocks) ----
    if (t == 0) {
        while (__hip_atomic_load(done + mt, __ATOMIC_RELAXED,
                                 __HIP_MEMORY_SCOPE_AGENT) < 16)
            __builtin_amdgcn_s_sleep(4);
        (void)__hip_atomic_load(done + mt, __ATOMIC_ACQUIRE,
                                __HIP_MEMORY_SCOPE_AGENT);  // cache-invalidate
    }
    __syncthreads();

    // ---- P5: K-loop + epilogue (identical structure to R6 v4) ----
    const long* BsL = (const long*)Bs;
    const long* Bp  = BsL + l;
#pragma unroll
    for (int p = 0; p < 2; p++) {
        const int mbase = m0 + w * 64 + p * 32;
        const long* Af = (const long*)A8f + (size_t)(mbase >> 5) * 2048 + l;

        v16f acc0 = (v16f)0.f, acc1 = (v16f)0.f;
#pragma unroll 4
        for (int kw = 0; kw < 32; kw++) {
            long a  = Af[kw * 64];
            long b0 = Bp[kw * 64];
            long b1 = Bp[2048 + kw * 64];
            acc0 = MFMA_F8(a, b0, acc0);
            acc1 = MFMA_F8(a, b1, acc1);
        }

        // C/D layout: col = l&31, row = (r&3) + 8*(r>>2) + 4*(l>>5).
        const float xv  = -0.5f * xsq[mbase + ln];
        const float mb0 = -0.5f * (mred[ln * 2] + mred[ln * 2 + 1]);
        const float mb1 = -0.5f * (mred[(32 + ln) * 2] + mred[(32 + ln) * 2 + 1]);
        float* obase = out + n0 + ln;
#pragma unroll
        for (int r = 0; r < 16; r++) {
            const int rl = (r & 3) + 8 * (r >> 2) + 4 * h;
            const float xb = __shfl(xv, rl, 64);
            float* orow = obase + (size_t)(mbase + rl) * UNITS;
            __builtin_nontemporal_store(__expf(acc0[r] + xb + mb0), orow);
            __builtin_nontemporal_store(__expf(acc1[r] + xb + mb1), orow + 32);
        }
    }
}

extern "C" void kernel_launch(void* const* d_in, const int* in_sizes, int n_in,
                              void* d_out, int out_size, void* d_ws, size_t ws_size,
                              hipStream_t stream) {
    const float* inputs = (const float*)d_in[0];   // [16384, 512] fp32
    const float* mu     = (const float*)d_in[1];   // [512, 1024] fp32
    float* out = (float*)d_out;                    // [16384, 1024] fp32

    char* ws = (char*)d_ws;
    unsigned char* A8f = (unsigned char*)ws;                       // 8 MiB
    float* xsq = (float*)(ws + (size_t)BATCH * DIM);               // 64 KiB
    int*   done = (int*)(ws + (size_t)BATCH * DIM + BATCH * 4);    // 256 B

    hipMemsetAsync(done, 0, 64 * sizeof(int), stream);             // zero flags
    rbf_fused_pc_kernel<<<1024, 256, 0, stream>>>(
        inputs, mu, A8f, xsq, done, out);
}

// Round 8
// 107.671 us; speedup vs baseline: 1.4614x; 1.4614x over previous
//
#include <hip/hip_runtime.h>

#define BATCH 16384
#define DIM   512
#define UNITS 1024
// GAMMA = 0.5 folded into epilogue: out = exp(cross - 0.5*xsq - 0.5*musq)

typedef float v16f __attribute__((ext_vector_type(16)));

#define BPITCH 33
#define MFMA_F8(a, b, c) __builtin_amdgcn_mfma_f32_32x32x16_fp8_fp8((a), (b), (c), 0, 0, 0)

static __device__ __forceinline__ int2 cvt8(const float4 f0, const float4 f1) {
    int lo = __builtin_amdgcn_cvt_pk_fp8_f32(f0.x, f0.y, 0, false);
    lo     = __builtin_amdgcn_cvt_pk_fp8_f32(f0.z, f0.w, lo, true);
    int hi = __builtin_amdgcn_cvt_pk_fp8_f32(f1.x, f1.y, 0, false);
    hi     = __builtin_amdgcn_cvt_pk_fp8_f32(f1.z, f1.w, hi, true);
    return make_int2(lo, hi);
}
static __device__ __forceinline__ float dot8(const float4 f0, const float4 f1) {
    return f0.x * f0.x + f0.y * f0.y + f0.z * f0.z + f0.w * f0.w
         + f1.x * f1.x + f1.y * f1.y + f1.z * f1.z + f1.w * f1.w;
}

// prep-B only (R0's proven B-path, standalone): 32 blocks x 256 threads.
// B8f: byte ((ng*32 + kw)*64 + lane)*8 — lane l holds
//   B[kw*16 + (l>>5)*8 + 0..7][ng*32 + (l&31)].  musq on fp32 values.
__global__ __launch_bounds__(256)
void prep_b_kernel(const float* __restrict__ mu, unsigned char* __restrict__ B8f,
                   float* __restrict__ musq) {
    __shared__ __attribute__((aligned(16))) char smem[512 * BPITCH * 4 + 1024];
    float* lds = (float*)smem;                       // [512][BPITCH]
    float* red = (float*)(smem + 512 * BPITCH * 4);  // [32][8]
    const int t  = threadIdx.x;
    const int l  = t & 63, w = t >> 6;
    const int ln = l & 31, h = l >> 5;
    const int nb = blockIdx.x;
    const int n0 = nb * 32;
    const int col = t & 31, kg = t >> 5;
    float s = 0.f;
    for (int i = 0; i < 64; i++) {
        const int k = i * 8 + kg;
        float v = mu[(size_t)k * UNITS + n0 + col];
        s += v * v;
        lds[k * BPITCH + col] = v;
    }
    red[col * 8 + kg] = s;
    __syncthreads();
    if (t < 32) {
        float a = 0.f;
#pragma unroll
        for (int i = 0; i < 8; i++) a += red[t * 8 + i];
        musq[n0 + t] = a;
    }
#pragma unroll
    for (int j = 0; j < 8; j++) {
        const int kw = w * 8 + j;
        const float* p = lds + (kw * 16 + h * 8) * BPITCH + ln;
        float f[8];
#pragma unroll
        for (int i = 0; i < 8; i++) f[i] = p[i * BPITCH];
        *(int2*)(B8f + (((size_t)nb * 32 + kw) * 64 + l) * 8) =
            cvt8(make_float4(f[0], f[1], f[2], f[3]),
                 make_float4(f[4], f[5], f[6], f[7]));
    }
}

// Main RBF kernel: 256 blocks x 1024 threads (16 waves), 1 block/CU,
// block tile 64M x 1024N — A is BLOCK-PRIVATE (no cross-block sharing,
// no A8f global round-trip, no prep-A kernel, no flags).
//  Stage rc=0,1: 32 A-rows -> LDS fp32 [32][516] (coalesced float4), barrier,
//    convert to fp8 fragments in LDS Afrag[rc] (R0's proven conflict-free
//    transpose-read pattern) + xsq partials; barrier.
//  xsq reduced into LDS (never leaves the block).
//  K-loop per wave (wr=w>>3 row-chunk, wc=w&7 col-128): TWO passes of
//    {32 kw x (1 ds_read A + 2 global B8f dwordx2 + 2 MFMA)} + exp/NT-store
//    epilogue per pass — stores interleave with compute; no barriers after
//    staging, waves drift. B8f (512 KB) is L2-resident per XCD.
__global__ __launch_bounds__(1024, 4)
void rbf_main_kernel(const float* __restrict__ in,
                     const unsigned char* __restrict__ B8f,
                     const float* __restrict__ musq,
                     float* __restrict__ out) {
    // LDS: stage 66048 | Afrag 32768 | red 8448 | xsq_l 256  = 107520 B
    __shared__ __attribute__((aligned(16))) unsigned char smem[107520];
    float* stage = (float*)smem;                         // [32][516] fp32
    unsigned char* Afrag = smem + 66048;                 // [2][32 kw][64 l][8]
    float* red   = (float*)(smem + 98816);               // [64][33]
    float* xsq_l = (float*)(smem + 107264);              // [64]

    const int t  = threadIdx.x;
    const int l  = t & 63;
    const int w  = t >> 6;          // wave 0..15
    const int ln = l & 31;
    const int h  = l >> 5;
    const int m0 = blockIdx.x * 64; // this block's 64 A-rows

    // ---- Stage + convert two 32-row chunks ----
#pragma unroll
    for (int rc = 0; rc < 2; rc++) {
        const float4* src = (const float4*)(in + (size_t)(m0 + rc * 32) * DIM);
        float4* s4 = (float4*)stage;
#pragma unroll
        for (int i = 0; i < 4; i++) {
            const int f = i * 1024 + t;                  // float4 id 0..4095
            s4[(f >> 7) * 129 + (f & 127)] = src[f];
        }
        __syncthreads();
        // convert: thread covers (row ln, k-half h) x kw = {w*2, w*2+1}
        float s = 0.f;
#pragma unroll
        for (int j = 0; j < 2; j++) {
            const int kw = w * 2 + j;
            const float* p = stage + ln * 516 + kw * 16 + h * 8;
            float4 f0 = *(const float4*)p;
            float4 f1 = *(const float4*)(p + 4);
            s += dot8(f0, f1);
            *(int2*)(Afrag + (((rc * 32 + kw) * 64) + h * 32 + ln) * 8) =
                cvt8(f0, f1);
        }
        red[(rc * 32 + ln) * 33 + w * 2 + h] = s;
        __syncthreads();
    }
    if (t < 64) {                   // xsq for all 64 rows, stays in LDS
        float a = 0.f;
#pragma unroll
        for (int i = 0; i < 32; i++) a += red[t * 33 + i];
        xsq_l[t] = -0.5f * a;
    }
    __syncthreads();                // last barrier; waves free-run from here

    // ---- Per-wave GEMM: rows [m0+wr*32,+32) x cols [wc*128,+128) ----
    const int wr = w >> 3;          // 0..1 row chunk
    const int wc = w & 7;           // 0..7 col group of 128
    const long* Af = (const long*)(Afrag + (size_t)wr * 16384);
    const long* Bg = (const long*)B8f + (size_t)(wc * 4) * 2048 + l;
    const size_t mrow = m0 + wr * 32;

#pragma unroll
    for (int g2 = 0; g2 < 2; g2++) {                     // two 64-col passes
        const long* B0 = Bg + (size_t)(g2 * 2) * 2048;
        const long* B1 = B0 + 2048;

        v16f acc0 = (v16f)0.f, acc1 = (v16f)0.f;
#pragma unroll 8
        for (int kw = 0; kw < 32; kw++) {
            long a  = Af[kw * 64 + l];
            long b0 = B0[kw * 64];
            long b1 = B1[kw * 64];
            acc0 = MFMA_F8(a, b0, acc0);
            acc1 = MFMA_F8(a, b1, acc1);
        }

        // Epilogue. C/D layout: col = l&31, row = (r&3) + 8*(r>>2) + 4*h.
        const int nc0 = wc * 128 + g2 * 64;
        const float mb0 = -0.5f * musq[nc0 + ln];
        const float mb1 = -0.5f * musq[nc0 + 32 + ln];
        float* obase = out + nc0 + ln;
#pragma unroll
        for (int r = 0; r < 16; r++) {
            const int rl = (r & 3) + 8 * (r >> 2) + 4 * h;
            const float xb = xsq_l[wr * 32 + rl];        // LDS broadcast
            float* orow = obase + (mrow + rl) * UNITS;
            __builtin_nontemporal_store(__expf(acc0[r] + xb + mb0), orow);
            __builtin_nontemporal_store(__expf(acc1[r] + xb + mb1), orow + 32);
        }
    }
}

extern "C" void kernel_launch(void* const* d_in, const int* in_sizes, int n_in,
                              void* d_out, int out_size, void* d_ws, size_t ws_size,
                              hipStream_t stream) {
    const float* inputs = (const float*)d_in[0];   // [16384, 512] fp32
    const float* mu     = (const float*)d_in[1];   // [512, 1024] fp32
    float* out = (float*)d_out;                    // [16384, 1024] fp32

    char* ws = (char*)d_ws;
    unsigned char* B8f = (unsigned char*)ws;                 // 512 KiB
    float* musq = (float*)(ws + (size_t)UNITS * DIM);        // 4 KiB

    prep_b_kernel<<<32, 256, 0, stream>>>(mu, B8f, musq);
    rbf_main_kernel<<<256, 1024, 0, stream>>>(inputs, B8f, musq, out);
}